// Round 21
// baseline (45.338 us; speedup 1.0000x reference)
//
#include <hip/hip_runtime.h>
#include <math.h>

#define NN 8192
#define MM 4096
#define DD 128
#define TDIM 32
#define H1DIM 64
#define H2DIM 32
#define FEAT (3*DD + TDIM)   // 416
#define NKS (FEAT/32)        // 13 k-steps
#define BIGF 1e30f

#define NCHUNK 512
#define RPC 16
#define CAP 8
#define LISTCAP 256
#define EDGES 8              // edges per stats block (group size)
#define NGRP (MM/EDGES)      // 512 groups -> 2+ blocks/CU

typedef float fvec4 __attribute__((ext_vector_type(4)));
typedef short bf16x8 __attribute__((ext_vector_type(8)));
typedef float f32x4  __attribute__((ext_vector_type(4)));

__device__ __forceinline__ unsigned short f2bf(float f) {
    unsigned int u = __builtin_bit_cast(unsigned int, f);
    u += 0x7FFF + ((u >> 16) & 1);              // RNE
    return (unsigned short)(u >> 16);
}
__device__ __forceinline__ unsigned int pack2bf(float a, float b) {
    return (unsigned int)f2bf(a) | ((unsigned int)f2bf(b) << 16);
}

// Node 1: chunked CSC scan, 8-edge-group-major output. Extra block packs
// W1 -> W1F (fragment-ordered bf16 for mfma_f32_16x16x32_bf16).
__global__ __launch_bounds__(256) void scan_csc(
        const float* __restrict__ H, const float* __restrict__ W1,
        unsigned short* __restrict__ idxg, unsigned char* __restrict__ cntg,
        unsigned short* __restrict__ W1F) {
    const int tid = threadIdx.x;
    const int c   = blockIdx.x;
    if (c == NCHUNK) {                       // W1F pack block
        for (int s = tid; s < 4 * NKS * 64; s += 256) {
            int n   = s / (NKS * 64);
            int rem = s % (NKS * 64);
            int ks  = rem / 64;
            int l   = rem % 64;
            const float* src = W1 + (16*n + (l & 15)) * FEAT
                                  + ks*32 + (l >> 4)*8;
            unsigned short* dst = W1F + (size_t)s * 8;
            #pragma unroll
            for (int i = 0; i < 8; ++i) dst[i] = f2bf(src[i]);
        }
        return;
    }

    __shared__ int lcnt[MM];
    for (int i = tid; i < MM; i += 256) lcnt[i] = 0;
    __syncthreads();

    const fvec4* H4 = reinterpret_cast<const fvec4*>(H) + (size_t)c * (RPC * MM / 4);
    const int r0 = c * RPC;

    for (int s = 0; s < 8; ++s) {            // 64 float4/thread, 8-deep batches
        fvec4 a[8]; int o[8];
        #pragma unroll
        for (int u = 0; u < 8; ++u) {
            o[u] = s * 2048 + u * 256 + tid;
            a[u] = H4[o[u]];
        }
        #pragma unroll
        for (int u = 0; u < 8; ++u) {
            fvec4 v = a[u];
            if (v.x != 0.f || v.y != 0.f || v.z != 0.f || v.w != 0.f) {
                int r  = r0 + (o[u] >> 10);
                int mb = (o[u] & 1023) * 4;
                float vals[4] = {v.x, v.y, v.z, v.w};
                #pragma unroll
                for (int q = 0; q < 4; ++q) {
                    if (vals[q] != 0.0f) {
                        int m = mb + q;
                        int p = atomicAdd(&lcnt[m], 1);
                        if (p < CAP) {
                            size_t cell = ((size_t)(m >> 3) * NCHUNK + c) * EDGES
                                          + (m & 7);
                            idxg[cell * CAP + p] = (unsigned short)r;
                        }
                    }
                }
            }
        }
    }
    __syncthreads();

    // counts: pack 8 counts per group -> one u64 store at cntg[g][c][0..8)
    for (int g = tid; g < NGRP; g += 256) {
        unsigned int w0 = 0, w1 = 0;
        #pragma unroll
        for (int q = 0; q < 4; ++q) {
            w0 |= (unsigned int)min(lcnt[g*8 + q],     CAP) << (8*q);
            w1 |= (unsigned int)min(lcnt[g*8 + 4 + q], CAP) << (8*q);
        }
        uint2* dst = (uint2*)(cntg + ((size_t)g * NCHUNK + c) * EDGES);
        *dst = make_uint2(w0, w1);
    }
}

// Node 2: merge + stats + MFMA-MLP. 512 blocks x 512 thr (8 waves), ~28 KB
// LDS -> 2-4 blocks/CU so blocks overlap each other's barrier bubbles.
__global__ __launch_bounds__(512) void stats_mlp(
        const float* __restrict__ x,
        const unsigned short* __restrict__ idxg, const unsigned char* __restrict__ cntg,
        const float* __restrict__ tptr, const float* __restrict__ Wt,
        const float* __restrict__ bt,
        const unsigned short* __restrict__ W1F, const float* __restrict__ b1,
        const float* __restrict__ W2, const float* __restrict__ b2,
        const float* __restrict__ W3, const float* __restrict__ b3,
        float* __restrict__ out) {
    __shared__ __attribute__((aligned(16))) unsigned char lsfB[16 * 832]; // bf16 [16][416]; rows 8-15 unused
    __shared__ float hs1[EDGES][H1DIM];                  // 2048 B
    __shared__ float w2t[H1DIM * H2DIM];                 // 8192 B
    __shared__ unsigned short lists[EDGES][LISTCAP];     // 4096 B
    __shared__ int lcnt2[EDGES];

    const int tid = threadIdx.x;
    const int wv  = tid >> 6, lane = tid & 63;
    const int g   = blockIdx.x;
    const int m0  = g * EDGES;

    for (int i = tid; i < H1DIM * H2DIM; i += 512)       // W2 -> LDS transp
        w2t[(i & 63) * H2DIM + (i >> 6)] = W2[i];        // w2t[k*32+j2]
    if (tid < EDGES) lcnt2[tid] = 0;
    __syncthreads();

    // ---- B1: merge (thread tid -> chunk tid; one u64 = whole count row) ----
    {
        const int c = tid;                    // 512 threads = 512 chunks
        const size_t cellbase = ((size_t)g * NCHUNK + c) * EDGES;
        unsigned long long k8 = *reinterpret_cast<const unsigned long long*>(
                                    cntg + cellbase);
        if (k8) {
            #pragma unroll
            for (int j = 0; j < 8; ++j) {
                int k = (int)((k8 >> (8 * j)) & 0xFF);
                if (k) {
                    uint4 s = *reinterpret_cast<const uint4*>(
                                  idxg + (cellbase + j) * CAP);
                    int base = atomicAdd(&lcnt2[j], k);
                    if (base + 8 <= LISTCAP) {
                        unsigned short* dst = &lists[j][base];
                        dst[0] = (unsigned short)(s.x & 0xFFFF);
                        if (k > 1) dst[1] = (unsigned short)(s.x >> 16);
                        if (k > 2) dst[2] = (unsigned short)(s.y & 0xFFFF);
                        if (k > 3) dst[3] = (unsigned short)(s.y >> 16);
                        if (k > 4) dst[4] = (unsigned short)(s.z & 0xFFFF);
                        if (k > 5) dst[5] = (unsigned short)(s.z >> 16);
                        if (k > 6) dst[6] = (unsigned short)(s.w & 0xFFFF);
                        if (k > 7) dst[7] = (unsigned short)(s.w >> 16);
                    }
                }
            }
        }
    }
    __syncthreads();

    // ---- B2: stats (wave wv -> edge wv), 8-deep gather batches ----
    {
        const float tval = tptr[0];
        int K = lcnt2[wv]; if (K > LISTCAP) K = LISTCAP;
        const unsigned short* lst = lists[wv];
        float sx = 0.f, sy = 0.f, s2x = 0.f, s2y = 0.f;
        float mxx = -BIGF, mxy = -BIGF, mnx = BIGF, mny = BIGF;
        const float* xb = x + 2 * lane;
        int i = 0;
        for (; i + 8 <= K; i += 8) {
            uint4 q = *reinterpret_cast<const uint4*>(lst + i);
            int n0 = q.x & 0xFFFF, n1 = q.x >> 16;
            int n2 = q.y & 0xFFFF, n3 = q.y >> 16;
            int n4 = q.z & 0xFFFF, n5 = q.z >> 16;
            int n6 = q.w & 0xFFFF, n7 = q.w >> 16;
            float2 v0 = *reinterpret_cast<const float2*>(xb + n0 * DD);
            float2 v1 = *reinterpret_cast<const float2*>(xb + n1 * DD);
            float2 v2 = *reinterpret_cast<const float2*>(xb + n2 * DD);
            float2 v3 = *reinterpret_cast<const float2*>(xb + n3 * DD);
            float2 v4 = *reinterpret_cast<const float2*>(xb + n4 * DD);
            float2 v5 = *reinterpret_cast<const float2*>(xb + n5 * DD);
            float2 v6 = *reinterpret_cast<const float2*>(xb + n6 * DD);
            float2 v7 = *reinterpret_cast<const float2*>(xb + n7 * DD);
            sx  += ((v0.x + v1.x) + (v2.x + v3.x)) + ((v4.x + v5.x) + (v6.x + v7.x));
            sy  += ((v0.y + v1.y) + (v2.y + v3.y)) + ((v4.y + v5.y) + (v6.y + v7.y));
            s2x += ((v0.x*v0.x + v1.x*v1.x) + (v2.x*v2.x + v3.x*v3.x))
                 + ((v4.x*v4.x + v5.x*v5.x) + (v6.x*v6.x + v7.x*v7.x));
            s2y += ((v0.y*v0.y + v1.y*v1.y) + (v2.y*v2.y + v3.y*v3.y))
                 + ((v4.y*v4.y + v5.y*v5.y) + (v6.y*v6.y + v7.y*v7.y));
            mxx = fmaxf(mxx, fmaxf(fmaxf(fmaxf(v0.x, v1.x), fmaxf(v2.x, v3.x)),
                                   fmaxf(fmaxf(v4.x, v5.x), fmaxf(v6.x, v7.x))));
            mxy = fmaxf(mxy, fmaxf(fmaxf(fmaxf(v0.y, v1.y), fmaxf(v2.y, v3.y)),
                                   fmaxf(fmaxf(v4.y, v5.y), fmaxf(v6.y, v7.y))));
            mnx = fminf(mnx, fminf(fminf(fminf(v0.x, v1.x), fminf(v2.x, v3.x)),
                                   fminf(fminf(v4.x, v5.x), fminf(v6.x, v7.x))));
            mny = fminf(mny, fminf(fminf(fminf(v0.y, v1.y), fminf(v2.y, v3.y)),
                                   fminf(fminf(v4.y, v5.y), fminf(v6.y, v7.y))));
        }
        for (; i < K; ++i) {
            float2 v = *reinterpret_cast<const float2*>(xb + (int)lst[i] * DD);
            sx += v.x; sy += v.y; s2x += v.x*v.x; s2y += v.y*v.y;
            mxx = fmaxf(mxx, v.x); mxy = fmaxf(mxy, v.y);
            mnx = fminf(mnx, v.x); mny = fminf(mny, v.y);
        }
        float deg = (K > 0) ? (float)K : 1.0f;
        float mux = sx / deg, muy = sy / deg;
        float sgx = sqrtf(fmaxf(s2x / deg - mux * mux, 1e-8f));
        float sgy = sqrtf(fmaxf(s2y / deg - muy * muy, 1e-8f));
        float dlx = (K > 0) ? (mxx - mnx) : 0.0f;
        float dly = (K > 0) ? (mxy - mny) : 0.0f;
        unsigned char* fb = lsfB + wv * 832;
        *reinterpret_cast<unsigned int*>(fb +       4*lane) = pack2bf(mux, muy);
        *reinterpret_cast<unsigned int*>(fb + 256 + 4*lane) = pack2bf(sgx, sgy);
        *reinterpret_cast<unsigned int*>(fb + 512 + 4*lane) = pack2bf(dlx, dly);
        if (lane < 16) {
            float t0 = fmaxf(tval * Wt[2*lane]     + bt[2*lane],     0.0f);
            float t1 = fmaxf(tval * Wt[2*lane + 1] + bt[2*lane + 1], 0.0f);
            *reinterpret_cast<unsigned int*>(fb + 768 + 4*lane) = pack2bf(t0, t1);
        }
    }
    __syncthreads();

    // ---- B3a: layer 1 via MFMA (waves 0-3: units [16wv,16wv+16)) ----
    // A rows 8-15 read unused LDS -> C rows 8-15 discarded (row-independent).
    if (wv < 4) {
        f32x4 acc = {0.f, 0.f, 0.f, 0.f};
        const bf16x8* Wf = reinterpret_cast<const bf16x8*>(W1F) + (wv * NKS) * 64 + lane;
        #pragma unroll
        for (int ks = 0; ks < NKS; ++ks) {
            bf16x8 a = *reinterpret_cast<const bf16x8*>(
                           lsfB + (lane & 15) * 832 + ks * 64 + (lane >> 4) * 16);
            bf16x8 b = Wf[ks * 64];
            acc = __builtin_amdgcn_mfma_f32_16x16x32_bf16(a, b, acc, 0, 0, 0);
        }
        float bias = b1[wv * 16 + (lane & 15)];
        #pragma unroll
        for (int i = 0; i < 4; ++i) {            // row=(lane>>4)*4+i
            int e = (lane >> 4) * 4 + i;
            if (e < EDGES)
                hs1[e][wv * 16 + (lane & 15)] = fmaxf(acc[i] + bias, 0.f);
        }
    }
    __syncthreads();

    // ---- B3b: layers 2+3 (wave wv -> row wv) ----
    {
        const int j2 = lane & 31;
        const int kh = (lane >> 5) * 32;
        float a2 = 0.f;
        #pragma unroll
        for (int kk = 0; kk < 32; ++kk) {
            int k = kh + kk;
            a2 += hs1[wv][k] * w2t[k * H2DIM + j2];
        }
        a2 += __shfl_xor(a2, 32);
        float h2 = fmaxf(a2 + b2[j2], 0.f);
        float p = h2 * W3[j2];
        p += __shfl_xor(p, 16);
        p += __shfl_xor(p, 8);
        p += __shfl_xor(p, 4);
        p += __shfl_xor(p, 2);
        p += __shfl_xor(p, 1);
        if (lane == 0) out[m0 + wv] = 1.f / (1.f + expf(-(p + b3[0])));
    }
}

extern "C" void kernel_launch(void* const* d_in, const int* in_sizes, int n_in,
                              void* d_out, int out_size, void* d_ws, size_t ws_size,
                              hipStream_t stream) {
    const float* x   = (const float*)d_in[0];   // (N, D)
    const float* H   = (const float*)d_in[1];   // (N, M)
    const float* t   = (const float*)d_in[2];   // (1,)
    const float* Wt  = (const float*)d_in[3];   // (TDIM, 1)
    const float* bt  = (const float*)d_in[4];   // (TDIM,)
    const float* W1  = (const float*)d_in[5];   // (64, 416)
    const float* b1  = (const float*)d_in[6];
    const float* W2  = (const float*)d_in[7];   // (32, 64)
    const float* b2  = (const float*)d_in[8];
    const float* W3  = (const float*)d_in[9];   // (1, 32)
    const float* b3  = (const float*)d_in[10];
    float* out = (float*)d_out;

    // workspace: idxg 32 MB; cntg 2 MB; W1F 52 KB
    unsigned short* idxg = (unsigned short*)d_ws;
    unsigned char*  cntg = (unsigned char*)(idxg + (size_t)NGRP * NCHUNK * EDGES * CAP);
    unsigned short* W1F  = (unsigned short*)(cntg + (size_t)NGRP * NCHUNK * EDGES);

    scan_csc<<<NCHUNK + 1, 256, 0, stream>>>(H, W1, idxg, cntg, W1F);
    stats_mlp<<<NGRP, 512, 0, stream>>>(
        x, idxg, cntg, t, Wt, bt, W1F, b1, W2, b2, W3, b3, out);
}

// Round 22
// 43.907 us; speedup vs baseline: 1.0326x; 1.0326x over previous
//
#include <hip/hip_runtime.h>
#include <math.h>

#define NN 8192
#define MM 4096
#define DD 128
#define TDIM 32
#define H1DIM 64
#define H2DIM 32
#define FEAT (3*DD + TDIM)   // 416
#define NKS (FEAT/32)        // 13 k-steps
#define BIGF 1e30f

#define NCHUNK 512
#define RPC 16
#define CAP 8
#define LISTCAP 256
#define EDGES 16
#define NGRP (MM/EDGES)      // 256

typedef float fvec4 __attribute__((ext_vector_type(4)));
typedef short bf16x8 __attribute__((ext_vector_type(8)));
typedef float f32x4  __attribute__((ext_vector_type(4)));

__device__ __forceinline__ unsigned short f2bf(float f) {
    unsigned int u = __builtin_bit_cast(unsigned int, f);
    u += 0x7FFF + ((u >> 16) & 1);              // RNE
    return (unsigned short)(u >> 16);
}
__device__ __forceinline__ unsigned int pack2bf(float a, float b) {
    return (unsigned int)f2bf(a) | ((unsigned int)f2bf(b) << 16);
}

// Node 1: chunked CSC scan, group-major output (R16-proven; warm scan =
// 20.7 us = 134 MB @ 6.5 TB/s = HBM read ceiling). Extra block packs
// W1 -> W1F: fragment-ordered bf16 for mfma_f32_16x16x32_bf16:
//   W1F[(((n*13)+ks)*64 + l)*8 + i] = bf16(W1[16n+(l&15)][ks*32+(l>>4)*8+i])
__global__ __launch_bounds__(256) void scan_csc(
        const float* __restrict__ H, const float* __restrict__ W1,
        unsigned short* __restrict__ idxg, unsigned char* __restrict__ cntg,
        unsigned short* __restrict__ W1F) {
    const int tid = threadIdx.x;
    const int c   = blockIdx.x;
    if (c == NCHUNK) {                       // W1F pack block
        for (int s = tid; s < 4 * NKS * 64; s += 256) {   // 3328 lane-slots
            int n   = s / (NKS * 64);
            int rem = s % (NKS * 64);
            int ks  = rem / 64;
            int l   = rem % 64;
            const float* src = W1 + (16*n + (l & 15)) * FEAT
                                  + ks*32 + (l >> 4)*8;
            unsigned short* dst = W1F + (size_t)s * 8;
            #pragma unroll
            for (int i = 0; i < 8; ++i) dst[i] = f2bf(src[i]);
        }
        return;
    }

    __shared__ int lcnt[MM];
    for (int i = tid; i < MM; i += 256) lcnt[i] = 0;
    __syncthreads();

    const fvec4* H4 = reinterpret_cast<const fvec4*>(H) + (size_t)c * (RPC * MM / 4);
    const int r0 = c * RPC;

    for (int s = 0; s < 8; ++s) {            // 64 float4/thread, 8-deep batches
        fvec4 a[8]; int o[8];
        #pragma unroll
        for (int u = 0; u < 8; ++u) {
            o[u] = s * 2048 + u * 256 + tid;
            a[u] = H4[o[u]];
        }
        #pragma unroll
        for (int u = 0; u < 8; ++u) {
            fvec4 v = a[u];
            if (v.x != 0.f || v.y != 0.f || v.z != 0.f || v.w != 0.f) {
                int r  = r0 + (o[u] >> 10);
                int mb = (o[u] & 1023) * 4;
                float vals[4] = {v.x, v.y, v.z, v.w};
                #pragma unroll
                for (int q = 0; q < 4; ++q) {
                    if (vals[q] != 0.0f) {
                        int m = mb + q;
                        int p = atomicAdd(&lcnt[m], 1);
                        if (p < CAP) {
                            size_t cell = ((size_t)(m >> 4) * NCHUNK + c) * EDGES
                                          + (m & 15);
                            idxg[cell * CAP + p] = (unsigned short)r;
                        }
                    }
                }
            }
        }
    }
    __syncthreads();

    {
        int g = tid;
        unsigned int w[4];
        #pragma unroll
        for (int q = 0; q < 4; ++q) {
            unsigned int k0 = min(lcnt[g*16 + 4*q + 0], CAP);
            unsigned int k1 = min(lcnt[g*16 + 4*q + 1], CAP);
            unsigned int k2 = min(lcnt[g*16 + 4*q + 2], CAP);
            unsigned int k3 = min(lcnt[g*16 + 4*q + 3], CAP);
            w[q] = k0 | (k1 << 8) | (k2 << 16) | (k3 << 24);
        }
        uint4* dst = (uint4*)(cntg + ((size_t)g * NCHUNK + c) * EDGES);
        *dst = make_uint4(w[0], w[1], w[2], w[3]);
    }
}

// Node 2: merge + stats + MFMA-MLP. 256 blocks x 1024 thr, ~34 KB static LDS.
//   B1: group-major merge (R16-proven)
//   B2: per-wave stats, 8-deep gather batches; features stored as bf16
//   B3: layer 1 = mfma_f32_16x16x32_bf16, waves 0-3 x {n-tile}, 13 k-steps;
//       layers 2+3 per-wave from fp32 hs1 (R16-proven shape)
__global__ __launch_bounds__(1024) void stats_mlp(
        const float* __restrict__ x,
        const unsigned short* __restrict__ idxg, const unsigned char* __restrict__ cntg,
        const float* __restrict__ tptr, const float* __restrict__ Wt,
        const float* __restrict__ bt,
        const unsigned short* __restrict__ W1F, const float* __restrict__ b1,
        const float* __restrict__ W2, const float* __restrict__ b2,
        const float* __restrict__ W3, const float* __restrict__ b3,
        float* __restrict__ out) {
    __shared__ __attribute__((aligned(16))) unsigned char lsfB[EDGES * 832]; // bf16 [16][416]
    __shared__ float hs1[EDGES][H1DIM];                  // 4096 B
    __shared__ float w2t[H1DIM * H2DIM];                 // 8192 B
    __shared__ unsigned short lists[EDGES][LISTCAP];     // 8192 B
    __shared__ int lcnt2[EDGES];

    const int tid = threadIdx.x;
    const int wv  = tid >> 6, lane = tid & 63;
    const int g   = blockIdx.x;
    const int m0  = g * EDGES;

    for (int i = tid; i < H1DIM * H2DIM; i += 1024)      // W2 -> LDS transp
        w2t[(i & 63) * H2DIM + (i >> 6)] = W2[i];        // w2t[k*32+j2]
    if (tid < EDGES) lcnt2[tid] = 0;
    __syncthreads();

    // ---- B1: merge group-major chunk segments into per-edge LDS lists ----
    {
        const int c  = tid >> 1;
        const int e0 = (tid & 1) * 8;
        const size_t cellbase = ((size_t)g * NCHUNK + c) * EDGES + e0;
        unsigned long long k8 = *reinterpret_cast<const unsigned long long*>(
                                    cntg + cellbase);
        if (k8) {
            #pragma unroll
            for (int j = 0; j < 8; ++j) {
                int k = (int)((k8 >> (8 * j)) & 0xFF);
                if (k) {
                    uint4 s = *reinterpret_cast<const uint4*>(
                                  idxg + (cellbase + j) * CAP);
                    int e = e0 + j;
                    int base = atomicAdd(&lcnt2[e], k);
                    if (base + 8 <= LISTCAP) {
                        unsigned short* dst = &lists[e][base];
                        dst[0] = (unsigned short)(s.x & 0xFFFF);
                        if (k > 1) dst[1] = (unsigned short)(s.x >> 16);
                        if (k > 2) dst[2] = (unsigned short)(s.y & 0xFFFF);
                        if (k > 3) dst[3] = (unsigned short)(s.y >> 16);
                        if (k > 4) dst[4] = (unsigned short)(s.z & 0xFFFF);
                        if (k > 5) dst[5] = (unsigned short)(s.z >> 16);
                        if (k > 6) dst[6] = (unsigned short)(s.w & 0xFFFF);
                        if (k > 7) dst[7] = (unsigned short)(s.w >> 16);
                    }
                }
            }
        }
    }
    __syncthreads();

    // ---- B2: stats (wave wv -> edge wv), 8-deep gather batches ----
    {
        const float tval = tptr[0];
        int K = lcnt2[wv]; if (K > LISTCAP) K = LISTCAP;
        const unsigned short* lst = lists[wv];
        float sx = 0.f, sy = 0.f, s2x = 0.f, s2y = 0.f;
        float mxx = -BIGF, mxy = -BIGF, mnx = BIGF, mny = BIGF;
        const float* xb = x + 2 * lane;
        int i = 0;
        for (; i + 8 <= K; i += 8) {
            uint4 q = *reinterpret_cast<const uint4*>(lst + i);   // 8 indices
            int n0 = q.x & 0xFFFF, n1 = q.x >> 16;
            int n2 = q.y & 0xFFFF, n3 = q.y >> 16;
            int n4 = q.z & 0xFFFF, n5 = q.z >> 16;
            int n6 = q.w & 0xFFFF, n7 = q.w >> 16;
            float2 v0 = *reinterpret_cast<const float2*>(xb + n0 * DD);
            float2 v1 = *reinterpret_cast<const float2*>(xb + n1 * DD);
            float2 v2 = *reinterpret_cast<const float2*>(xb + n2 * DD);
            float2 v3 = *reinterpret_cast<const float2*>(xb + n3 * DD);
            float2 v4 = *reinterpret_cast<const float2*>(xb + n4 * DD);
            float2 v5 = *reinterpret_cast<const float2*>(xb + n5 * DD);
            float2 v6 = *reinterpret_cast<const float2*>(xb + n6 * DD);
            float2 v7 = *reinterpret_cast<const float2*>(xb + n7 * DD);
            sx  += ((v0.x + v1.x) + (v2.x + v3.x)) + ((v4.x + v5.x) + (v6.x + v7.x));
            sy  += ((v0.y + v1.y) + (v2.y + v3.y)) + ((v4.y + v5.y) + (v6.y + v7.y));
            s2x += ((v0.x*v0.x + v1.x*v1.x) + (v2.x*v2.x + v3.x*v3.x))
                 + ((v4.x*v4.x + v5.x*v5.x) + (v6.x*v6.x + v7.x*v7.x));
            s2y += ((v0.y*v0.y + v1.y*v1.y) + (v2.y*v2.y + v3.y*v3.y))
                 + ((v4.y*v4.y + v5.y*v5.y) + (v6.y*v6.y + v7.y*v7.y));
            mxx = fmaxf(mxx, fmaxf(fmaxf(fmaxf(v0.x, v1.x), fmaxf(v2.x, v3.x)),
                                   fmaxf(fmaxf(v4.x, v5.x), fmaxf(v6.x, v7.x))));
            mxy = fmaxf(mxy, fmaxf(fmaxf(fmaxf(v0.y, v1.y), fmaxf(v2.y, v3.y)),
                                   fmaxf(fmaxf(v4.y, v5.y), fmaxf(v6.y, v7.y))));
            mnx = fminf(mnx, fminf(fminf(fminf(v0.x, v1.x), fminf(v2.x, v3.x)),
                                   fminf(fminf(v4.x, v5.x), fminf(v6.x, v7.x))));
            mny = fminf(mny, fminf(fminf(fminf(v0.y, v1.y), fminf(v2.y, v3.y)),
                                   fminf(fminf(v4.y, v5.y), fminf(v6.y, v7.y))));
        }
        for (; i < K; ++i) {
            float2 v = *reinterpret_cast<const float2*>(xb + (int)lst[i] * DD);
            sx += v.x; sy += v.y; s2x += v.x*v.x; s2y += v.y*v.y;
            mxx = fmaxf(mxx, v.x); mxy = fmaxf(mxy, v.y);
            mnx = fminf(mnx, v.x); mny = fminf(mny, v.y);
        }
        float deg = (K > 0) ? (float)K : 1.0f;
        float mux = sx / deg, muy = sy / deg;
        float sgx = sqrtf(fmaxf(s2x / deg - mux * mux, 1e-8f));
        float sgy = sqrtf(fmaxf(s2y / deg - muy * muy, 1e-8f));
        float dlx = (K > 0) ? (mxx - mnx) : 0.0f;
        float dly = (K > 0) ? (mxy - mny) : 0.0f;
        // features -> LDS as packed bf16 (k=2*lane, 2*lane+1 per section)
        unsigned char* fb = lsfB + wv * 832;
        *reinterpret_cast<unsigned int*>(fb +       4*lane) = pack2bf(mux, muy);
        *reinterpret_cast<unsigned int*>(fb + 256 + 4*lane) = pack2bf(sgx, sgy);
        *reinterpret_cast<unsigned int*>(fb + 512 + 4*lane) = pack2bf(dlx, dly);
        if (lane < 16) {
            float t0 = fmaxf(tval * Wt[2*lane]     + bt[2*lane],     0.0f);
            float t1 = fmaxf(tval * Wt[2*lane + 1] + bt[2*lane + 1], 0.0f);
            *reinterpret_cast<unsigned int*>(fb + 768 + 4*lane) = pack2bf(t0, t1);
        }
    }
    __syncthreads();

    // ---- B3a: layer 1 via MFMA (waves 0-3: n-tile wv => units [16wv,16wv+16)) ----
    if (wv < 4) {
        f32x4 acc = {0.f, 0.f, 0.f, 0.f};
        const bf16x8* Wf = reinterpret_cast<const bf16x8*>(W1F) + (wv * NKS) * 64 + lane;
        #pragma unroll
        for (int ks = 0; ks < NKS; ++ks) {
            bf16x8 a = *reinterpret_cast<const bf16x8*>(
                           lsfB + (lane & 15) * 832 + ks * 64 + (lane >> 4) * 16);
            bf16x8 b = Wf[ks * 64];              // coalesced 1KB/wave, L2-hot
            acc = __builtin_amdgcn_mfma_f32_16x16x32_bf16(a, b, acc, 0, 0, 0);
        }
        float bias = b1[wv * 16 + (lane & 15)];
        #pragma unroll
        for (int i = 0; i < 4; ++i) {            // C: col=lane&15, row=(lane>>4)*4+i
            int e = (lane >> 4) * 4 + i;
            hs1[e][wv * 16 + (lane & 15)] = fmaxf(acc[i] + bias, 0.f);
        }
    }
    __syncthreads();

    // ---- B3b: layers 2+3 (wave wv -> row wv; R16-proven) ----
    {
        const int j2 = lane & 31;
        const int kh = (lane >> 5) * 32;
        float a2 = 0.f;
        #pragma unroll
        for (int kk = 0; kk < 32; ++kk) {
            int k = kh + kk;
            a2 += hs1[wv][k] * w2t[k * H2DIM + j2];
        }
        a2 += __shfl_xor(a2, 32);
        float h2 = fmaxf(a2 + b2[j2], 0.f);
        float p = h2 * W3[j2];
        p += __shfl_xor(p, 16);
        p += __shfl_xor(p, 8);
        p += __shfl_xor(p, 4);
        p += __shfl_xor(p, 2);
        p += __shfl_xor(p, 1);
        if (lane == 0) out[m0 + wv] = 1.f / (1.f + expf(-(p + b3[0])));
    }
}

extern "C" void kernel_launch(void* const* d_in, const int* in_sizes, int n_in,
                              void* d_out, int out_size, void* d_ws, size_t ws_size,
                              hipStream_t stream) {
    const float* x   = (const float*)d_in[0];   // (N, D)
    const float* H   = (const float*)d_in[1];   // (N, M)
    const float* t   = (const float*)d_in[2];   // (1,)
    const float* Wt  = (const float*)d_in[3];   // (TDIM, 1)
    const float* bt  = (const float*)d_in[4];   // (TDIM,)
    const float* W1  = (const float*)d_in[5];   // (64, 416)
    const float* b1  = (const float*)d_in[6];
    const float* W2  = (const float*)d_in[7];   // (32, 64)
    const float* b2  = (const float*)d_in[8];
    const float* W3  = (const float*)d_in[9];   // (1, 32)
    const float* b3  = (const float*)d_in[10];
    float* out = (float*)d_out;

    // workspace: idxg 32 MB; cntg 2 MB; W1F 4*13*64*8 bf16 = 52 KB
    unsigned short* idxg = (unsigned short*)d_ws;
    unsigned char*  cntg = (unsigned char*)(idxg + (size_t)NGRP * NCHUNK * EDGES * CAP);
    unsigned short* W1F  = (unsigned short*)(cntg + (size_t)NGRP * NCHUNK * EDGES);

    scan_csc<<<NCHUNK + 1, 256, 0, stream>>>(H, W1, idxg, cntg, W1F);
    stats_mlp<<<NGRP, 1024, 0, stream>>>(
        x, idxg, cntg, t, Wt, bt, W1F, b1, W2, b2, W3, b3, out);
}